// Round 12
// baseline (3321.124 us; speedup 1.0000x reference)
//
#include <hip/hip_runtime.h>
#include <math.h>

#define Bn 16
#define Tn 16384
#define Fn 32
#define Cn 64
#define Ln 10
#define ST 76   // LDS tile row stride (elements): 152B -> conflict-free patterns

typedef _Float16 v8h  __attribute__((ext_vector_type(8)));
typedef _Float16 v4h  __attribute__((ext_vector_type(4)));
typedef float    v16f __attribute__((ext_vector_type(16)));
typedef float    v4f  __attribute__((ext_vector_type(4)));

// ---------------------------------------------------------------------------
// Software grid barrier (device-scope atomics).  Cooperative launch is NOT
// stream-capturable (R5): counter + generation word in d_ws, memset each
// launch.  Deadlock-safety is COMPILE-TIME GUARANTEED here:
// __launch_bounds__(512,4) forces VGPR<=128 (4 waves/EU min), so 2 blocks/CU
// (16 waves) always fit; LDS 38912B*2=77.8KB<=160KB; capacity 2*256=512 =
// grid -> all blocks resident.
// ---------------------------------------------------------------------------
__device__ __forceinline__ void gbarrier(unsigned* bar, unsigned nblk, unsigned phase)
{
    __syncthreads();
    if (threadIdx.x == 0) {
        __threadfence();
        unsigned prev = __hip_atomic_fetch_add(&bar[0], 1u, __ATOMIC_ACQ_REL,
                                               __HIP_MEMORY_SCOPE_AGENT);
        if (prev == nblk - 1u) {
            __hip_atomic_store(&bar[0], 0u, __ATOMIC_RELAXED, __HIP_MEMORY_SCOPE_AGENT);
            __hip_atomic_store(&bar[1], phase, __ATOMIC_RELEASE, __HIP_MEMORY_SCOPE_AGENT);
        } else {
            while (__hip_atomic_load(&bar[1], __ATOMIC_ACQUIRE,
                                     __HIP_MEMORY_SCOPE_AGENT) < phase)
                __builtin_amdgcn_s_sleep(2);
        }
        __threadfence();
    }
    __syncthreads();
}

// ---------------------------------------------------------------------------
// Fully-fused WaveNet, one kernel + software barriers — 8-WAVE BLOCKS.
// R6-R10 lesson: the regalloc refuses >128 VGPRs (chose 64 at cap 128, 128 at
// cap 256, spilling ~700MB either way).  Fix the GEOMETRY instead: 512-thread
// blocks halve per-thread state — sk = 512t*64c/512thr = 32 regs, acc = one
// v16f pair = 32 regs (F/G reused as R/S) -> ~120 live <= 128 budget.
//  - 512 blocks x 512 threads; block owns 512-t span (4 tiles of 128t),
//    XCD-sliced (j&7 = XCD), identical slice every layer -> L2-local h.
//  - wave (of 8) owns a 32co x 32t quarter: ch32=wv&1, tq=wv>>1.
//  - skip accumulator in REGISTERS across all 10 layers (sk[4][4] v4h).
//  - 9 gbarriers between layers; skip NEVER touches HBM (kills 64MB/layer).
//  - last layer: hout write + R epilogue skipped.
// mfma_f32_32x32x16_f16: A[m=lane&31][k=(lane>>5)*8+j], B[k][n=lane&31],
// D: col(n)=lane&31, row(m)=(reg&3)+8*(reg>>2)+4*(lane>>5).
// ---------------------------------------------------------------------------
__global__ __launch_bounds__(512, 4) void k_fused(
    const float* __restrict__ x,
    const float* __restrict__ w_in, const float* __restrict__ b_in,
    const float* __restrict__ fw,  const float* __restrict__ gw,
    const float* __restrict__ rw,  const float* __restrict__ sw,
    const float* __restrict__ fb,  const float* __restrict__ gb,
    const float* __restrict__ rb,  const float* __restrict__ sb,
    const float* __restrict__ ow1, const float* __restrict__ ob1,
    const float* __restrict__ ow2, const float* __restrict__ ob2,
    float* __restrict__ out,
    _Float16* __restrict__ hA, _Float16* __restrict__ hB,
    _Float16* __restrict__ wfgP, _Float16* __restrict__ rsP,
    unsigned* __restrict__ bar)
{
    __shared__ _Float16 SH[2 * 128 * ST];          // 38912B, multi-purpose
    _Float16* const P0 = SH;
    _Float16* const P1 = SH + 128 * ST;

    const int tid  = threadIdx.x;       // 0..511
    const int lane = tid & 63;
    const int wv   = tid >> 6;          // 0..7
    const int ch32 = wv & 1;
    const int ch   = ch32 * 32;         // co-half
    const int tw   = (wv >> 1) * 32;    // t-quarter offset within 128-tile
    const int hl   = lane >> 5;
    const int ln31 = lane & 31;
    const int bb   = blockIdx.x >> 5;   // 32 blocks per batch
    const int j    = blockIdx.x & 31;
    const int tBase = ((j & 7) * 4 + (j >> 3)) * 512;   // 512-t span, XCD-sliced
    const size_t hbase = (size_t)bb * Tn * 64;

    v8h zero8;
    #pragma unroll
    for (int z = 0; z < 8; ++z) zero8[z] = (_Float16)0.f;

    // coalesced staging: thread covers 2 x (row, 8c) cells of a 128-row tile
    const int s_tl = tid >> 3;              // base row (0..63), rows step 64
    const int s_c  = (tid & 7) * 8;

    // ---- phase P: weight packing fp32 -> fp16 fragment order (grid-stride)
    {
        const int total1 = Ln * 24576;
        for (int gid = blockIdx.x * 512 + tid; gid < total1; gid += 512 * 512) {
            int l = gid / 24576, rem = gid % 24576;
            int chunk = rem >> 9, within = rem & 511;
            int ll = within >> 3, jj = within & 7;
            int c32 = chunk & 1, fg = (chunk >> 1) & 1;
            int kc = (chunk >> 2) & 3, tap = chunk >> 4;
            int co = c32 * 32 + (ll & 31);
            int ci = kc * 16 + (ll >> 5) * 8 + jj;
            const float* wsrc = fg ? gw : fw;
            wfgP[gid] = (_Float16)wsrc[((l * 64 + co) * 64 + ci) * 3 + tap];
        }
        const int total2 = Ln * 8192;
        for (int gid = blockIdx.x * 512 + tid; gid < total2; gid += 512 * 512) {
            int l = gid / 8192, rem = gid % 8192;
            int chunk = rem >> 9, within = rem & 511;
            int ll = within >> 3, jj = within & 7;
            int c32 = chunk & 1, rsi = (chunk >> 1) & 1, kc = chunk >> 2;
            int co = c32 * 32 + (ll & 31);
            int ci = kc * 16 + (ll >> 5) * 8 + jj;
            const float* wsrc = rsi ? sw : rw;
            rsP[gid] = (_Float16)wsrc[(l * 64 + co) * 64 + ci];
        }
    }

    // ---- phase I: input 1x1 conv -> hA for this block's 512 t.
    // tid>>8 selects c-half (wave-uniform!), tid&255 selects t -> w_in/b_in
    // indices loop-uniform -> scalar loads.  Stores via LDS rotation ->
    // flat contiguous global stores.
    {
        const int c32sel = tid >> 8;        // 0/1, uniform within a wave
        const int tI     = tid & 255;
        #pragma unroll
        for (int u = 0; u < 2; ++u) {
            const int t0c = tBase + u * 256;
            const float* xp = x + ((size_t)bb * Tn + t0c + tI) * Fn;
            float xv[32];
            #pragma unroll
            for (int i = 0; i < 8; ++i) {
                v4f v = *(const v4f*)&xp[i * 4];
                xv[i*4+0] = v[0]; xv[i*4+1] = v[1]; xv[i*4+2] = v[2]; xv[i*4+3] = v[3];
            }
            #pragma unroll
            for (int c8 = 0; c8 < 4; ++c8) {
                v8h o;
                #pragma unroll
                for (int jj = 0; jj < 8; ++jj) {
                    int c = c32sel * 32 + c8 * 8 + jj;   // loop-uniform -> s_loads
                    float a = b_in[c];
                    #pragma unroll
                    for (int f = 0; f < 32; ++f) a = fmaf(w_in[c * 32 + f], xv[f], a);
                    o[jj] = (_Float16)a;
                }
                const int ck = c32sel * 4 + c8;          // chunk index 0..7
                const int p  = (ck + tI) & 7;            // bank-rotate slot
                *(v8h*)&SH[tI * 64 + p * 8] = o;
            }
            __syncthreads();
            _Float16* hp = hA + ((size_t)bb * Tn + t0c) * 64;
            #pragma unroll
            for (int it = 0; it < 4; ++it) {
                const int g = it * 512 + tid;            // 2048 16B chunks
                const int tl = g >> 3, c8g = g & 7;
                const int p = (c8g + tl) & 7;
                *(v8h*)&hp[g * 8] = *(const v8h*)&SH[tl * 64 + p * 8];
            }
            __syncthreads();
        }
    }

    gbarrier(bar, 512, 1);                          // weights + h0 visible

    // persistent skip accumulator: [tile][q], static-indexed -> 32 VGPRs
    v4h sk[4][4];

    const _Float16* cur = hA;
    _Float16* nxt = hB;

#define STAGE(DST, OFF) do {                                                  \
    _Pragma("unroll")                                                         \
    for (int it = 0; it < 2; ++it) {                                          \
        int tl = s_tl + it * 64;                                              \
        int tg = t0 + tl - (OFF);                                             \
        v8h v = zero8;                                                        \
        if (tg >= 0) v = *(const v8h*)&cur[hbase + (size_t)tg * 64 + s_c];    \
        *(v8h*)&(DST)[tl * ST + s_c] = v;                                     \
    } } while (0)

#define WOFF(TAP, KC, FG) (((((TAP) * 4 + (KC)) * 2 + (FG)) * 2 + ch32) * 512 + lane * 8)
#define RSOFF(KC, RSI)    ((((KC) * 2 + (RSI)) * 2 + ch32) * 512 + lane * 8)

#define MFMA_TAP(SRC, TAP) do {                                               \
    _Pragma("unroll")                                                         \
    for (int kc = 0; kc < 4; ++kc) {                                          \
        const int kof = kc * 16 + hl * 8;                                     \
        v8h aF = *(const v8h*)&wfg[WOFF(TAP, kc, 0)];                         \
        v8h aG = *(const v8h*)&wfg[WOFF(TAP, kc, 1)];                         \
        v8h b0 = *(const v8h*)&(SRC)[(tw + ln31) * ST + kof];                 \
        accF = __builtin_amdgcn_mfma_f32_32x32x16_f16(aF, b0, accF, 0, 0, 0); \
        accG = __builtin_amdgcn_mfma_f32_32x32x16_f16(aG, b0, accG, 0, 0, 0); \
    } } while (0)

    #pragma unroll 1
    for (int l = 0; l < Ln; ++l) {
        const int dil = 1 << l;
        const _Float16* wfg = wfgP + (size_t)l * 24576;
        const _Float16* rs  = rsP  + (size_t)l * 8192;
        const float* fbl = fb + l * Cn;
        const float* gbl = gb + l * Cn;
        const float* rbl = rb + l * Cn;
        const float* sbl = sb + l * Cn;
        const bool last = (l == Ln - 1);

        #pragma unroll
        for (int tile = 0; tile < 4; ++tile) {
            const int t0 = tBase + tile * 128;

            // biases -> accumulator init (D row m -> c = ch + 8q + 4hl + r)
            v16f accF, accG;
            #pragma unroll
            for (int q = 0; q < 4; ++q) {
                v4f fv = *(const v4f*)&fbl[ch + 8 * q + 4 * hl];
                v4f gv = *(const v4f*)&gbl[ch + 8 * q + 4 * hl];
                #pragma unroll
                for (int r = 0; r < 4; ++r) {
                    accF[q * 4 + r] = fv[r];
                    accG[q * 4 + r] = gv[r];
                }
            }

            STAGE(P0, 2 * dil);
            __syncthreads();                        // S1: P0 ready
            STAGE(P1, dil);                         // overlap tap1 loads w/ tap0 mfma
            MFMA_TAP(P0, 0);
            __syncthreads();                        // S2: P1 ready, P0 reads done
            STAGE(P0, 0);                           // overlap tap2 loads w/ tap1 mfma
            MFMA_TAP(P1, 1);
            __syncthreads();                        // S3: P0 ready, P1 reads done
            MFMA_TAP(P0, 2);                        // P0 holds hin[t] - kept

            // act = tanh(f)*sigmoid(g) = (A-1)*rcp((A+1)*(1+B)) -> P1 scatter
            // (wave's own 32t x 32c quarter)
            #pragma unroll
            for (int q = 0; q < 4; ++q) {
                v4h av;
                #pragma unroll
                for (int r = 0; r < 4; ++r) {
                    float f = accF[q * 4 + r];
                    float g = accG[q * 4 + r];
                    float A = __expf(2.f * f);
                    float B = __expf(-g);
                    float tA = A + 1.f;
                    float den = fmaf(tA, B, tA);
                    av[r] = (_Float16)((A - 1.f) * __builtin_amdgcn_rcpf(den));
                }
                *(v4h*)&P1[(tw + ln31) * ST + ch + 8 * q + 4 * hl] = av;
            }
            __syncthreads();                        // S4: act done (cross c-half dep)

            // accF/accG reused as R/S accumulators (disjoint lifetime)
            #pragma unroll
            for (int q = 0; q < 4; ++q) {
                v4f rv = *(const v4f*)&rbl[ch + 8 * q + 4 * hl];
                v4f sv = *(const v4f*)&sbl[ch + 8 * q + 4 * hl];
                #pragma unroll
                for (int r = 0; r < 4; ++r) {
                    accF[q * 4 + r] = rv[r];
                    accG[q * 4 + r] = sv[r];
                }
            }
            #pragma unroll
            for (int kc = 0; kc < 4; ++kc) {
                const int kof = kc * 16 + hl * 8;
                v8h aR = *(const v8h*)&rs[RSOFF(kc, 0)];
                v8h aS = *(const v8h*)&rs[RSOFF(kc, 1)];
                v8h b0 = *(const v8h*)&P1[(tw + ln31) * ST + kof];
                accF = __builtin_amdgcn_mfma_f32_32x32x16_f16(aR, b0, accF, 0, 0, 0);
                accG = __builtin_amdgcn_mfma_f32_32x32x16_f16(aS, b0, accG, 0, 0, 0);
            }

            // R epilogue in-place on P0: h_new = (h + R)*0.7071 (dead last layer)
            if (!last) {
                #pragma unroll
                for (int q = 0; q < 4; ++q) {
                    _Float16* cell = &P0[(tw + ln31) * ST + ch + 8 * q + 4 * hl];
                    v4h hv = *(const v4h*)cell;
                    v4h hn;
                    #pragma unroll
                    for (int r = 0; r < 4; ++r)
                        hn[r] = (_Float16)(((float)hv[r] + accF[q * 4 + r]) * 0.7071f);
                    *(v4h*)cell = hn;
                }
            }

            // skip accumulation IN REGISTERS (no HBM RMW)
            #pragma unroll
            for (int q = 0; q < 4; ++q) {
                v4h sn;
                #pragma unroll
                for (int r = 0; r < 4; ++r) {
                    float v = accG[q * 4 + r];
                    if (l) v += (float)sk[tile][q][r];
                    sn[r] = (_Float16)v;
                }
                sk[tile][q] = sn;
            }
            __syncthreads();                        // S5: P0 hout complete, P1 free

            // hout coalesced store from P0 (dead for last layer).
            // No S6 needed: next tile's STAGE writes P0 at the same
            // (s_tl,s_c) cells this thread reads here.
            if (!last) {
                #pragma unroll
                for (int it = 0; it < 2; ++it) {
                    int tl = s_tl + it * 64;
                    *(v8h*)&nxt[hbase + (size_t)(t0 + tl) * 64 + s_c] =
                        *(const v8h*)&P0[tl * ST + s_c];
                }
            }
        }

        if (!last) {
            gbarrier(bar, 512, (unsigned)(l + 2));  // layer complete device-wide
            _Float16* tmp = nxt; nxt = (_Float16*)cur; cur = tmp;
        }
    }
#undef STAGE
#undef MFMA_TAP
#undef WOFF
#undef RSOFF

    __syncthreads();                                // LDS free for phase O

    // ---- phase O: skip regs -> LDS transpose -> 2-layer MLP -> out ----
    // Per pass: 2 tiles (256 t); SH stride 68 halfs breaks bank aliasing.
    #pragma unroll
    for (int u = 0; u < 2; ++u) {
        #pragma unroll
        for (int tl2 = 0; tl2 < 2; ++tl2) {
            const int tile = u * 2 + tl2;
            #pragma unroll
            for (int q = 0; q < 4; ++q) {
                const int row = tl2 * 128 + tw + ln31;
                *(v4h*)&SH[row * 68 + ch + 8 * q + 4 * hl] = sk[tile][q];
            }
        }
        __syncthreads();
        if (tid < 256) {
            const int t = tBase + u * 256 + tid;    // one t per thread
            float y[64];
            #pragma unroll
            for (int i = 0; i < 16; ++i) {
                v4h v = *(const v4h*)&SH[tid * 68 + i * 4];
                #pragma unroll
                for (int r = 0; r < 4; ++r) y[i * 4 + r] = fmaxf((float)v[r], 0.f);
            }
            float o = ob2[0];
            for (int co = 0; co < 64; ++co) {       // weights uniform -> s_loads
                float a0 = ob1[co], a1 = 0.f;
                #pragma unroll
                for (int ci = 0; ci < 64; ci += 2) {
                    a0 = fmaf(ow1[co * 64 + ci],     y[ci],     a0);
                    a1 = fmaf(ow1[co * 64 + ci + 1], y[ci + 1], a1);
                }
                o = fmaf(ow2[co], fmaxf(a0 + a1, 0.f), o);
            }
            out[(size_t)bb * Tn + t] = o;
        }
        __syncthreads();                            // SH reusable for u=1
    }
}

// ---------------------------------------------------------------------------
extern "C" void kernel_launch(void* const* d_in, const int* in_sizes, int n_in,
                              void* d_out, int out_size, void* d_ws, size_t ws_size,
                              hipStream_t stream)
{
    const float* x    = (const float*)d_in[0];
    const float* w_in = (const float*)d_in[1];
    const float* b_in = (const float*)d_in[2];
    const float* fw   = (const float*)d_in[3];
    const float* fb   = (const float*)d_in[4];
    const float* gw   = (const float*)d_in[5];
    const float* gb   = (const float*)d_in[6];
    const float* rw   = (const float*)d_in[7];
    const float* rb   = (const float*)d_in[8];
    const float* sw   = (const float*)d_in[9];
    const float* sb   = (const float*)d_in[10];
    const float* ow1  = (const float*)d_in[11];
    const float* ob1  = (const float*)d_in[12];
    const float* ow2  = (const float*)d_in[13];
    const float* ob2  = (const float*)d_in[14];
    float* out = (float*)d_out;

    const size_t n = (size_t)Bn * Tn * 64;
    _Float16* hA   = (_Float16*)d_ws;
    _Float16* hB   = hA + n;
    _Float16* wfgP = hB + n;
    _Float16* rsP  = wfgP + (size_t)Ln * 24576;
    unsigned* bar  = (unsigned*)(rsP + (size_t)Ln * 8192);

    hipMemsetAsync(bar, 0, 2 * sizeof(unsigned), stream);
    k_fused<<<dim3(512), dim3(512), 0, stream>>>(
        x, w_in, b_in, fw, gw, rw, sw, fb, gb, rb, sb,
        ow1, ob1, ow2, ob2, out, hA, hB, wfgP, rsP, bar);
}

// Round 13
// 549.612 us; speedup vs baseline: 6.0427x; 6.0427x over previous
//
#include <hip/hip_runtime.h>
#include <math.h>

#define Bn 16
#define Tn 16384
#define Fn 32
#define Cn 64
#define Ln 10
#define ST 76   // LDS tile row stride (elements): 152B -> conflict-free patterns

typedef _Float16 v8h  __attribute__((ext_vector_type(8)));
typedef _Float16 v4h  __attribute__((ext_vector_type(4)));
typedef float    v16f __attribute__((ext_vector_type(16)));
typedef float    v4f  __attribute__((ext_vector_type(4)));

// ---------------------------------------------------------------------------
// k_prep: pack weights fp32 -> fp16 in PER-LANE FRAGMENT ORDER so k_layer's
// A-operand loads are fully coalesced (16B/lane, 1KB/wave bursts).
// wfgP[l][chunk][lane][8]:  chunk = ((tap*4 + kc)*2 + fg)*2 + ch32
// rsP [l][chunk][lane][8]:  chunk = (kc*2 + rsi)*2 + ch32
// ---------------------------------------------------------------------------
__global__ __launch_bounds__(256) void k_prep(const float* __restrict__ fw,
                                              const float* __restrict__ gw,
                                              const float* __restrict__ rw,
                                              const float* __restrict__ sw,
                                              _Float16* __restrict__ wfgP,
                                              _Float16* __restrict__ rsP)
{
    int gid = blockIdx.x * 256 + threadIdx.x;
    if (gid < Ln * 24576) {
        int l      = gid / 24576;
        int rem    = gid % 24576;
        int chunk  = rem >> 9;
        int within = rem & 511;
        int lane   = within >> 3, j = within & 7;
        int ch32 = chunk & 1;
        int fg   = (chunk >> 1) & 1;
        int kc   = (chunk >> 2) & 3;
        int tap  = chunk >> 4;
        int co = ch32 * 32 + (lane & 31);
        int ci = kc * 16 + (lane >> 5) * 8 + j;
        const float* wsrc = fg ? gw : fw;
        wfgP[gid] = (_Float16)wsrc[((l * 64 + co) * 64 + ci) * 3 + tap];
    }
    int gid2 = gid - Ln * 24576;
    if (gid2 >= 0 && gid2 < Ln * 8192) {
        int l      = gid2 / 8192;
        int rem    = gid2 % 8192;
        int chunk  = rem >> 9;
        int within = rem & 511;
        int lane   = within >> 3, j = within & 7;
        int ch32 = chunk & 1;
        int rsi  = (chunk >> 1) & 1;
        int kc   = chunk >> 2;
        int co = ch32 * 32 + (lane & 31);
        int ci = kc * 16 + (lane >> 5) * 8 + j;
        const float* wsrc = rsi ? sw : rw;
        rsP[gid2] = (_Float16)wsrc[(l * 64 + co) * 64 + ci];
    }
}

// ---------------------------------------------------------------------------
// XCD-aware block swizzle: blocks with the same (bx % 8) = same XCD own a
// contiguous t-slice; identical slice ownership (2048 t per XCD per batch)
// across ALL kernels/layers keeps h/skip XCD-L2-local.  nblk % 8 == 0.
// ---------------------------------------------------------------------------
__device__ __forceinline__ int xcd_swizzle(int bx, int nblk)
{
    return (bx & 7) * (nblk >> 3) + (bx >> 3);
}

// ---------------------------------------------------------------------------
// k_input: h[b][t][c] = fp16( sum_f w_in[c][f] * x[b][t][f] + b_in[c] )
// One thread per t -> w_in/b_in loop-uniform -> scalar loads; stores via
// LDS rotation -> flat contiguous global stores (no write amplification).
// ---------------------------------------------------------------------------
__global__ __launch_bounds__(256) void k_input(const float* __restrict__ x,
                                               const float* __restrict__ w_in,
                                               const float* __restrict__ b_in,
                                               _Float16* __restrict__ h)
{
    __shared__ _Float16 HT[256 * 64];   // 32KB
    const int tid = threadIdx.x;
    const int blk = xcd_swizzle(blockIdx.x, Tn / 256);
    const int t0  = blk * 256;
    const int t   = t0 + tid;
    const int bb  = blockIdx.y;
    const float* xp = x + ((size_t)bb * Tn + t) * Fn;
    float xv[32];
    #pragma unroll
    for (int i = 0; i < 8; ++i) {
        v4f v = *(const v4f*)&xp[i * 4];
        xv[i*4+0] = v[0]; xv[i*4+1] = v[1]; xv[i*4+2] = v[2]; xv[i*4+3] = v[3];
    }
    #pragma unroll
    for (int c8 = 0; c8 < 8; ++c8) {
        v8h o;
        #pragma unroll
        for (int j = 0; j < 8; ++j) {
            int c = c8 * 8 + j;                 // loop-uniform -> s_loads
            float a = b_in[c];
            #pragma unroll
            for (int f = 0; f < 32; ++f) a = fmaf(w_in[c * 32 + f], xv[f], a);
            o[j] = (_Float16)a;
        }
        const int p = (c8 + tid) & 7;           // bank-rotate chunk slot
        *(v8h*)&HT[tid * 64 + p * 8] = o;
    }
    __syncthreads();
    _Float16* hp = h + ((size_t)bb * Tn + t0) * 64;
    #pragma unroll
    for (int it = 0; it < 8; ++it) {
        const int g  = it * 256 + tid;
        const int tl = g >> 3, c8 = g & 7;
        const int p  = (c8 + tl) & 7;
        *(v8h*)&hp[g * 8] = *(const v8h*)&HT[tl * 64 + p * 8];
    }
}

// ---------------------------------------------------------------------------
// k_layer: one WaveNet layer, 64-t tiles (R12 lesson: fusion spills — revert
// to R3 multi-kernel; R3 lesson: k_layer delivers only 2.5 TB/s at 31% occ,
// LDS 38.9KB caps 4 blk/CU).  Halving the tile halves LDS (19.5KB -> 8
// blk/CU cap) and halves accumulator regs (wave owns 32co x 32t quarter,
// single v16f per acc) -> ~2x resident blocks -> more concurrent phase
// chains across the vmcnt(0)-draining barriers -> higher HBM delivery.
// Block 256 = 4 waves; tile 64co x 64t; wave tile 32co x 32t.
// mfma_f32_32x32x16_f16: A[m=lane&31][k=(lane>>5)*8+j], B[k][n=lane&31],
// D: col(n)=lane&31, row(m)=(reg&3)+8*(reg>>2)+4*(lane>>5).
// ---------------------------------------------------------------------------
__global__ __launch_bounds__(256, 4) void k_layer(
    const _Float16* __restrict__ hin, _Float16* __restrict__ hout,
    _Float16* __restrict__ skip,
    const _Float16* __restrict__ wfg,   // fragment-ordered, 48*512 halfs
    const _Float16* __restrict__ rs,    // fragment-ordered, 16*512 halfs
    const float* __restrict__ fb, const float* __restrict__ gb,
    const float* __restrict__ rb, const float* __restrict__ sb,
    const int dil, const float skip_scale)
{
    __shared__ _Float16 P0[64 * ST];    // 9.7KB
    __shared__ _Float16 P1[64 * ST];    // 9.7KB -> total 19.5KB

    const int tid  = threadIdx.x;
    const int lane = tid & 63;
    const int wv   = tid >> 6;          // 0..3
    const int ch32 = wv & 1;
    const int ch   = ch32 * 32;         // co-half
    const int tw   = (wv >> 1) * 32;    // t-half of the 64-t tile
    const int hl   = lane >> 5;
    const int ln31 = lane & 31;
    const int bb   = blockIdx.y;
    const int t0   = xcd_swizzle(blockIdx.x, Tn / 64) * 64;
    const size_t hbase = (size_t)bb * Tn * 64;

    v8h zero8;
    #pragma unroll
    for (int j = 0; j < 8; ++j) zero8[j] = (_Float16)0.f;

    // coalesced tap staging: thread covers 2 x (tl, 8c) cells of 64 rows
    const int s_tl = tid >> 3;              // base row (0..31), rows step 32
    const int s_c  = (tid & 7) * 8;

#define STAGE(DST, OFF) do {                                                  \
    _Pragma("unroll")                                                         \
    for (int it = 0; it < 2; ++it) {                                          \
        int tl = s_tl + it * 32;                                              \
        int tg = t0 + tl - (OFF);                                             \
        v8h v = zero8;                                                        \
        if (tg >= 0) v = *(const v8h*)&hin[hbase + (size_t)tg * 64 + s_c];    \
        *(v8h*)&(DST)[tl * ST + s_c] = v;                                     \
    } } while (0)

// fragment-ordered weight load offsets (coalesced: 16B/lane)
#define WOFF(TAP, KC, FG) (((((TAP) * 4 + (KC)) * 2 + (FG)) * 2 + ch32) * 512 + lane * 8)
#define RSOFF(KC, RSI)    ((((KC) * 2 + (RSI)) * 2 + ch32) * 512 + lane * 8)

#define MFMA_TAP(SRC, TAP) do {                                               \
    _Pragma("unroll")                                                         \
    for (int kc = 0; kc < 4; ++kc) {                                          \
        const int kof = kc * 16 + hl * 8;                                     \
        v8h aF = *(const v8h*)&wfg[WOFF(TAP, kc, 0)];                         \
        v8h aG = *(const v8h*)&wfg[WOFF(TAP, kc, 1)];                         \
        v8h b0 = *(const v8h*)&(SRC)[(tw + ln31) * ST + kof];                 \
        accF = __builtin_amdgcn_mfma_f32_32x32x16_f16(aF, b0, accF, 0, 0, 0); \
        accG = __builtin_amdgcn_mfma_f32_32x32x16_f16(aG, b0, accG, 0, 0, 0); \
    } } while (0)

    // biases -> accumulator init (D row m maps to c = ch + 8q + 4hl + r)
    v16f accF, accG;
    #pragma unroll
    for (int q = 0; q < 4; ++q) {
        v4f fv = *(const v4f*)&fb[ch + 8 * q + 4 * hl];
        v4f gv = *(const v4f*)&gb[ch + 8 * q + 4 * hl];
        #pragma unroll
        for (int r = 0; r < 4; ++r) {
            accF[q * 4 + r] = fv[r];
            accG[q * 4 + r] = gv[r];
        }
    }

    STAGE(P0, 2 * dil);
    __syncthreads();                        // S1: P0 ready
    STAGE(P1, dil);                         // overlap tap1 loads with tap0 mfma
    MFMA_TAP(P0, 0);
    __syncthreads();                        // S2: P1 ready, P0 reads done
    STAGE(P0, 0);                           // overlap tap2 loads with tap1 mfma
    MFMA_TAP(P1, 1);
    __syncthreads();                        // S3: P0 ready, P1 reads done
    MFMA_TAP(P0, 2);                        // P0 now holds hin[t] (off=0) - kept

    // act = tanh(f)*sigmoid(g) = (A-1)*rcp((A+1)*(1+B)), A=e^2f, B=e^-g
    // -> P1 [t][ci] scatter (wave's own 32t x 32c quarter)
    #pragma unroll
    for (int q = 0; q < 4; ++q) {
        v4h av;
        #pragma unroll
        for (int r = 0; r < 4; ++r) {
            float f = accF[q * 4 + r];
            float g = accG[q * 4 + r];
            float A = __expf(2.f * f);
            float B = __expf(-g);
            float tA = A + 1.f;
            float den = fmaf(tA, B, tA);
            av[r] = (_Float16)((A - 1.f) * __builtin_amdgcn_rcpf(den));
        }
        *(v4h*)&P1[(tw + ln31) * ST + ch + 8 * q + 4 * hl] = av;
    }
    __syncthreads();                        // S4: act complete (cross c-half dep)

    // biases -> accR/accS init
    v16f accR, accS;
    #pragma unroll
    for (int q = 0; q < 4; ++q) {
        v4f rv = *(const v4f*)&rb[ch + 8 * q + 4 * hl];
        v4f sv = *(const v4f*)&sb[ch + 8 * q + 4 * hl];
        #pragma unroll
        for (int r = 0; r < 4; ++r) {
            accR[q * 4 + r] = rv[r];
            accS[q * 4 + r] = sv[r];
        }
    }

    #pragma unroll
    for (int kc = 0; kc < 4; ++kc) {
        const int kof = kc * 16 + hl * 8;
        v8h aR = *(const v8h*)&rs[RSOFF(kc, 0)];
        v8h aS = *(const v8h*)&rs[RSOFF(kc, 1)];
        v8h b0 = *(const v8h*)&P1[(tw + ln31) * ST + kof];
        accR = __builtin_amdgcn_mfma_f32_32x32x16_f16(aR, b0, accR, 0, 0, 0);
        accS = __builtin_amdgcn_mfma_f32_32x32x16_f16(aS, b0, accS, 0, 0, 0);
    }

    // R epilogue in-place on P0 (holds hin tile): h_new = (h + R)*0.7071
    #pragma unroll
    for (int q = 0; q < 4; ++q) {
        _Float16* cell = &P0[(tw + ln31) * ST + ch + 8 * q + 4 * hl];
        v4h hv = *(const v4h*)cell;
        v4h hn;
        #pragma unroll
        for (int r = 0; r < 4; ++r)
            hn[r] = (_Float16)(((float)hv[r] + accR[q * 4 + r]) * 0.7071f);
        *(v4h*)cell = hn;
    }
    __syncthreads();                        // S5: P1 rs-reads done, P0 = hout tile

    // S scatter -> P1 (act dead): skip contribution (bias already in accS)
    #pragma unroll
    for (int q = 0; q < 4; ++q) {
        v4h sn;
        #pragma unroll
        for (int r = 0; r < 4; ++r)
            sn[r] = (_Float16)accS[q * 4 + r];
        *(v4h*)&P1[(tw + ln31) * ST + ch + 8 * q + 4 * hl] = sn;
    }
    // hout coalesced store from P0 (safe after S5)
    #pragma unroll
    for (int it = 0; it < 2; ++it) {
        int tl = s_tl + it * 32;
        *(v8h*)&hout[hbase + (size_t)(t0 + tl) * 64 + s_c] = *(const v8h*)&P0[tl * ST + s_c];
    }
    __syncthreads();                        // S6: P1 skip tile complete

    // skip coalesced RMW from P1
    #pragma unroll
    for (int it = 0; it < 2; ++it) {
        int tl = s_tl + it * 32;
        const size_t base = hbase + (size_t)(t0 + tl) * 64 + s_c;
        v8h sk = *(const v8h*)&skip[base];
        v8h pv = *(const v8h*)&P1[tl * ST + s_c];
        v8h sn;
        #pragma unroll
        for (int r = 0; r < 8; ++r)
            sn[r] = (_Float16)((float)sk[r] * skip_scale + (float)pv[r]);
        *(v8h*)&skip[base] = sn;
    }
#undef STAGE
#undef MFMA_TAP
#undef WOFF
#undef RSOFF
}

// ---------------------------------------------------------------------------
// k_out: out[b][t] = ow2 @ relu(ow1 @ relu(skip[b][t][:]) + ob1) + ob2
// ---------------------------------------------------------------------------
__global__ __launch_bounds__(256) void k_out(const _Float16* __restrict__ skip,
                                             const float* __restrict__ ow1,
                                             const float* __restrict__ ob1,
                                             const float* __restrict__ ow2,
                                             const float* __restrict__ ob2,
                                             float* __restrict__ out)
{
    const int blk = xcd_swizzle(blockIdx.x, Tn / 256);
    const int t  = blk * 256 + threadIdx.x;
    const int bb = blockIdx.y;
    const _Float16* sp = skip + ((size_t)bb * Tn + t) * 64;
    float y[64];
    #pragma unroll
    for (int i = 0; i < 8; ++i) {
        v8h v = *(const v8h*)&sp[i * 8];
        #pragma unroll
        for (int j = 0; j < 8; ++j) y[i * 8 + j] = fmaxf((float)v[j], 0.f);
    }
    float o = ob2[0];
    for (int co = 0; co < 64; ++co) {          // weights uniform -> s_loads
        float a0 = ob1[co], a1 = 0.f;
        #pragma unroll
        for (int ci = 0; ci < 64; ci += 2) {
            a0 = fmaf(ow1[co * 64 + ci],     y[ci],     a0);
            a1 = fmaf(ow1[co * 64 + ci + 1], y[ci + 1], a1);
        }
        o = fmaf(ow2[co], fmaxf(a0 + a1, 0.f), o);
    }
    out[(size_t)bb * Tn + t] = o;
}

// ---------------------------------------------------------------------------
extern "C" void kernel_launch(void* const* d_in, const int* in_sizes, int n_in,
                              void* d_out, int out_size, void* d_ws, size_t ws_size,
                              hipStream_t stream)
{
    const float* x    = (const float*)d_in[0];
    const float* w_in = (const float*)d_in[1];
    const float* b_in = (const float*)d_in[2];
    const float* fw   = (const float*)d_in[3];
    const float* fb   = (const float*)d_in[4];
    const float* gw   = (const float*)d_in[5];
    const float* gb   = (const float*)d_in[6];
    const float* rw   = (const float*)d_in[7];
    const float* rb   = (const float*)d_in[8];
    const float* sw   = (const float*)d_in[9];
    const float* sb   = (const float*)d_in[10];
    const float* ow1  = (const float*)d_in[11];
    const float* ob1  = (const float*)d_in[12];
    const float* ow2  = (const float*)d_in[13];
    const float* ob2  = (const float*)d_in[14];
    float* out = (float*)d_out;

    const size_t n = (size_t)Bn * Tn * 64;
    _Float16* hA    = (_Float16*)d_ws;
    _Float16* hB    = hA + n;
    _Float16* skip  = hB + n;
    _Float16* wfg16 = skip + n;
    _Float16* rs16  = wfg16 + (size_t)Ln * 24576;

    dim3 blk(256);
    k_prep<<<dim3((Ln * 24576 + Ln * 8192 + 255) / 256), blk, 0, stream>>>(
        fw, gw, rw, sw, wfg16, rs16);
    k_input<<<dim3(Tn / 256, Bn), blk, 0, stream>>>(x, w_in, b_in, hA);

    const _Float16* cur = hA;
    _Float16* nxt = hB;
    for (int l = 0; l < Ln; ++l) {
        const int d = 1 << l;                  // dilations 1..512
        k_layer<<<dim3(Tn / 64, Bn), blk, 0, stream>>>(
            cur, nxt, skip,
            wfg16 + (size_t)l * 24576, rs16 + (size_t)l * 8192,
            fb + l * Cn, gb + l * Cn, rb + l * Cn, sb + l * Cn,
            d, (l == 0) ? 0.f : 1.f);          // scale=0 absorbs 0xAA ws poison
        const _Float16* tmp = nxt; nxt = (_Float16*)cur; cur = tmp;
    }

    k_out<<<dim3(Tn / 256, Bn), blk, 0, stream>>>(skip, ow1, ob1, ow2, ob2, out);
}

// Round 14
// 534.748 us; speedup vs baseline: 6.2106x; 1.0278x over previous
//
#include <hip/hip_runtime.h>
#include <math.h>

#define Bn 16
#define Tn 16384
#define Fn 32
#define Cn 64
#define Ln 10
#define ST 76   // LDS tile row stride (elements): 152B -> conflict-free patterns

typedef _Float16 v8h  __attribute__((ext_vector_type(8)));
typedef _Float16 v4h  __attribute__((ext_vector_type(4)));
typedef float    v16f __attribute__((ext_vector_type(16)));
typedef float    v4f  __attribute__((ext_vector_type(4)));

// ---------------------------------------------------------------------------
// k_prep: pack weights fp32 -> fp16 in PER-LANE FRAGMENT ORDER so k_layer's
// A-operand loads are fully coalesced (16B/lane, 1KB/wave bursts).
// wfgP[l][chunk][lane][8]:  chunk = ((tap*4 + kc)*2 + fg)*2 + ch32
// rsP [l][chunk][lane][8]:  chunk = (kc*2 + rsi)*2 + ch32
// ---------------------------------------------------------------------------
__global__ __launch_bounds__(256) void k_prep(const float* __restrict__ fw,
                                              const float* __restrict__ gw,
                                              const float* __restrict__ rw,
                                              const float* __restrict__ sw,
                                              _Float16* __restrict__ wfgP,
                                              _Float16* __restrict__ rsP)
{
    int gid = blockIdx.x * 256 + threadIdx.x;
    if (gid < Ln * 24576) {
        int l      = gid / 24576;
        int rem    = gid % 24576;
        int chunk  = rem >> 9;
        int within = rem & 511;
        int lane   = within >> 3, j = within & 7;
        int ch32 = chunk & 1;
        int fg   = (chunk >> 1) & 1;
        int kc   = (chunk >> 2) & 3;
        int tap  = chunk >> 4;
        int co = ch32 * 32 + (lane & 31);
        int ci = kc * 16 + (lane >> 5) * 8 + j;
        const float* wsrc = fg ? gw : fw;
        wfgP[gid] = (_Float16)wsrc[((l * 64 + co) * 64 + ci) * 3 + tap];
    }
    int gid2 = gid - Ln * 24576;
    if (gid2 >= 0 && gid2 < Ln * 8192) {
        int l      = gid2 / 8192;
        int rem    = gid2 % 8192;
        int chunk  = rem >> 9;
        int within = rem & 511;
        int lane   = within >> 3, j = within & 7;
        int ch32 = chunk & 1;
        int rsi  = (chunk >> 1) & 1;
        int kc   = chunk >> 2;
        int co = ch32 * 32 + (lane & 31);
        int ci = kc * 16 + (lane >> 5) * 8 + j;
        const float* wsrc = rsi ? sw : rw;
        rsP[gid2] = (_Float16)wsrc[(l * 64 + co) * 64 + ci];
    }
}

// ---------------------------------------------------------------------------
// XCD-aware block swizzle: blocks with the same (bx % 8) = same XCD own a
// contiguous t-slice; identical slice ownership across ALL kernels/layers
// keeps h/skip XCD-L2-local.  nblk % 8 == 0.
// ---------------------------------------------------------------------------
__device__ __forceinline__ int xcd_swizzle(int bx, int nblk)
{
    return (bx & 7) * (nblk >> 3) + (bx >> 3);
}

// ---------------------------------------------------------------------------
// k_input: h[b][t][c] = fp16( sum_f w_in[c][f] * x[b][t][f] + b_in[c] )
// One thread per t -> w_in/b_in loop-uniform -> scalar loads; stores via
// LDS rotation -> flat contiguous global stores (no write amplification).
// ---------------------------------------------------------------------------
__global__ __launch_bounds__(256) void k_input(const float* __restrict__ x,
                                               const float* __restrict__ w_in,
                                               const float* __restrict__ b_in,
                                               _Float16* __restrict__ h)
{
    __shared__ _Float16 HT[256 * 64];   // 32KB
    const int tid = threadIdx.x;
    const int blk = xcd_swizzle(blockIdx.x, Tn / 256);
    const int t0  = blk * 256;
    const int t   = t0 + tid;
    const int bb  = blockIdx.y;
    const float* xp = x + ((size_t)bb * Tn + t) * Fn;
    float xv[32];
    #pragma unroll
    for (int i = 0; i < 8; ++i) {
        v4f v = *(const v4f*)&xp[i * 4];
        xv[i*4+0] = v[0]; xv[i*4+1] = v[1]; xv[i*4+2] = v[2]; xv[i*4+3] = v[3];
    }
    #pragma unroll
    for (int c8 = 0; c8 < 8; ++c8) {
        v8h o;
        #pragma unroll
        for (int j = 0; j < 8; ++j) {
            int c = c8 * 8 + j;                 // loop-uniform -> s_loads
            float a = b_in[c];
            #pragma unroll
            for (int f = 0; f < 32; ++f) a = fmaf(w_in[c * 32 + f], xv[f], a);
            o[j] = (_Float16)a;
        }
        const int p = (c8 + tid) & 7;           // bank-rotate chunk slot
        *(v8h*)&HT[tid * 64 + p * 8] = o;
    }
    __syncthreads();
    _Float16* hp = h + ((size_t)bb * Tn + t0) * 64;
    #pragma unroll
    for (int it = 0; it < 8; ++it) {
        const int g  = it * 256 + tid;
        const int tl = g >> 3, c8 = g & 7;
        const int p  = (c8 + tl) & 7;
        *(v8h*)&hp[g * 8] = *(const v8h*)&HT[tl * 64 + p * 8];
    }
}

// ---------------------------------------------------------------------------
// k_layer_u: layers with d <= 32 — UNION staging.  The three tap windows
// {t-2d, t-d, t} all lie in [t0-64, t0+64), so stage that 128-row window
// ONCE (4 loads/thread vs 6), run all 24 tap-MFMAs back-to-back, then reuse
// the dead lower half (rows [0,64) = t < t0) for act and skip tiles.
// Barriers 6 -> 5, staging phases 3 -> 1, LDS identical 19456B.
// UB row r <-> global t = t0 - 64 + r; hin tile = rows [64,128) (kept
// intact for the residual epilogue).
// Block 256 = 4 waves; tile 64co x 64t; wave tile 32co x 32t.
// mfma_f32_32x32x16_f16: A[m=lane&31][k=(lane>>5)*8+j], B[k][n=lane&31],
// D: col(n)=lane&31, row(m)=(reg&3)+8*(reg>>2)+4*(lane>>5).
// ---------------------------------------------------------------------------
__global__ __launch_bounds__(256, 4) void k_layer_u(
    const _Float16* __restrict__ hin, _Float16* __restrict__ hout,
    _Float16* __restrict__ skip,
    const _Float16* __restrict__ wfg,   // fragment-ordered, 48*512 halfs
    const _Float16* __restrict__ rs,    // fragment-ordered, 16*512 halfs
    const float* __restrict__ fb, const float* __restrict__ gb,
    const float* __restrict__ rb, const float* __restrict__ sb,
    const int dil, const float skip_scale)
{
    __shared__ _Float16 UB[128 * ST];   // 19456B

    const int tid  = threadIdx.x;
    const int lane = tid & 63;
    const int wv   = tid >> 6;          // 0..3
    const int ch32 = wv & 1;
    const int ch   = ch32 * 32;         // co-half
    const int tw   = (wv >> 1) * 32;    // t-half of the 64-t tile
    const int hl   = lane >> 5;
    const int ln31 = lane & 31;
    const int bb   = blockIdx.y;
    const int t0   = xcd_swizzle(blockIdx.x, Tn / 64) * 64;
    const size_t hbase = (size_t)bb * Tn * 64;

    v8h zero8;
    #pragma unroll
    for (int j = 0; j < 8; ++j) zero8[j] = (_Float16)0.f;

    const int s_tl = tid >> 3;              // base row (0..31), rows step 32
    const int s_c  = (tid & 7) * 8;

#define WOFF(TAP, KC, FG) (((((TAP) * 4 + (KC)) * 2 + (FG)) * 2 + ch32) * 512 + lane * 8)
#define RSOFF(KC, RSI)    ((((KC) * 2 + (RSI)) * 2 + ch32) * 512 + lane * 8)

    // ---- single union stage: rows [0,128) <-> t in [t0-64, t0+64)
    #pragma unroll
    for (int it = 0; it < 4; ++it) {
        int row = s_tl + it * 32;
        int tg  = t0 - 64 + row;
        v8h v = zero8;
        if (tg >= 0) v = *(const v8h*)&hin[hbase + (size_t)tg * 64 + s_c];
        *(v8h*)&UB[row * ST + s_c] = v;
    }

    // biases -> accumulator init (D row m maps to c = ch + 8q + 4hl + r)
    v16f accF, accG;
    #pragma unroll
    for (int q = 0; q < 4; ++q) {
        v4f fv = *(const v4f*)&fb[ch + 8 * q + 4 * hl];
        v4f gv = *(const v4f*)&gb[ch + 8 * q + 4 * hl];
        #pragma unroll
        for (int r = 0; r < 4; ++r) {
            accF[q * 4 + r] = fv[r];
            accG[q * 4 + r] = gv[r];
        }
    }
    __syncthreads();                        // S1: U ready

    // all 24 tap MFMAs back-to-back; tap TAP reads hin[t - (2-TAP)*d]
    #pragma unroll
    for (int tap = 0; tap < 3; ++tap) {
        const int rbase = 64 + tw - (2 - tap) * dil;
        #pragma unroll
        for (int kc = 0; kc < 4; ++kc) {
            const int kof = kc * 16 + hl * 8;
            v8h aF = *(const v8h*)&wfg[WOFF(tap, kc, 0)];
            v8h aG = *(const v8h*)&wfg[WOFF(tap, kc, 1)];
            v8h b0 = *(const v8h*)&UB[(rbase + ln31) * ST + kof];
            accF = __builtin_amdgcn_mfma_f32_32x32x16_f16(aF, b0, accF, 0, 0, 0);
            accG = __builtin_amdgcn_mfma_f32_32x32x16_f16(aG, b0, accG, 0, 0, 0);
        }
    }
    __syncthreads();                        // S2: all U reads done; rows [0,64) dead

    // act = tanh(f)*sigmoid(g) = (A-1)*rcp((A+1)*(1+B)) -> rows [0,64) as A-tile
    #pragma unroll
    for (int q = 0; q < 4; ++q) {
        v4h av;
        #pragma unroll
        for (int r = 0; r < 4; ++r) {
            float f = accF[q * 4 + r];
            float g = accG[q * 4 + r];
            float A = __expf(2.f * f);
            float B = __expf(-g);
            float tA = A + 1.f;
            float den = fmaf(tA, B, tA);
            av[r] = (_Float16)((A - 1.f) * __builtin_amdgcn_rcpf(den));
        }
        *(v4h*)&UB[(tw + ln31) * ST + ch + 8 * q + 4 * hl] = av;
    }
    __syncthreads();                        // S3: act tile ready

    // RS MFMA from act tile (rows [0,64))
    v16f accR, accS;
    #pragma unroll
    for (int q = 0; q < 4; ++q) {
        v4f rv = *(const v4f*)&rb[ch + 8 * q + 4 * hl];
        v4f sv = *(const v4f*)&sb[ch + 8 * q + 4 * hl];
        #pragma unroll
        for (int r = 0; r < 4; ++r) {
            accR[q * 4 + r] = rv[r];
            accS[q * 4 + r] = sv[r];
        }
    }
    #pragma unroll
    for (int kc = 0; kc < 4; ++kc) {
        const int kof = kc * 16 + hl * 8;
        v8h aR = *(const v8h*)&rs[RSOFF(kc, 0)];
        v8h aS = *(const v8h*)&rs[RSOFF(kc, 1)];
        v8h b0 = *(const v8h*)&UB[(tw + ln31) * ST + kof];
        accR = __builtin_amdgcn_mfma_f32_32x32x16_f16(aR, b0, accR, 0, 0, 0);
        accS = __builtin_amdgcn_mfma_f32_32x32x16_f16(aS, b0, accS, 0, 0, 0);
    }

    // R epilogue in-place on hin tile (rows [64,128), own quarter, no race)
    #pragma unroll
    for (int q = 0; q < 4; ++q) {
        _Float16* cell = &UB[(64 + tw + ln31) * ST + ch + 8 * q + 4 * hl];
        v4h hv = *(const v4h*)cell;
        v4h hn;
        #pragma unroll
        for (int r = 0; r < 4; ++r)
            hn[r] = (_Float16)(((float)hv[r] + accR[q * 4 + r]) * 0.7071f);
        *(v4h*)cell = hn;
    }
    __syncthreads();                        // S4: all RS reads done; rows [0,64) free

    // skip scatter -> rows [0,64) (bias already in accS)
    #pragma unroll
    for (int q = 0; q < 4; ++q) {
        v4h sn;
        #pragma unroll
        for (int r = 0; r < 4; ++r)
            sn[r] = (_Float16)accS[q * 4 + r];
        *(v4h*)&UB[(tw + ln31) * ST + ch + 8 * q + 4 * hl] = sn;
    }
    __syncthreads();                        // S5: hout + skip tiles complete

    // coalesced stores: hout from rows [64,128), skip RMW from rows [0,64)
    #pragma unroll
    for (int it = 0; it < 2; ++it) {
        int tl = s_tl + it * 32;
        *(v8h*)&hout[hbase + (size_t)(t0 + tl) * 64 + s_c] =
            *(const v8h*)&UB[(64 + tl) * ST + s_c];
    }
    #pragma unroll
    for (int it = 0; it < 2; ++it) {
        int tl = s_tl + it * 32;
        const size_t base = hbase + (size_t)(t0 + tl) * 64 + s_c;
        v8h sk = *(const v8h*)&skip[base];
        v8h pv = *(const v8h*)&UB[tl * ST + s_c];
        v8h sn;
        #pragma unroll
        for (int r = 0; r < 8; ++r)
            sn[r] = (_Float16)((float)sk[r] * skip_scale + (float)pv[r]);
        *(v8h*)&skip[base] = sn;
    }
#undef WOFF
#undef RSOFF
}

// ---------------------------------------------------------------------------
// k_layer: layers with d > 32 (tap windows disjoint) — R13 structure.
// Block 256 = 4 waves; tile 64co x 64t; wave tile 32co x 32t; LDS 19.5KB.
// ---------------------------------------------------------------------------
__global__ __launch_bounds__(256, 4) void k_layer(
    const _Float16* __restrict__ hin, _Float16* __restrict__ hout,
    _Float16* __restrict__ skip,
    const _Float16* __restrict__ wfg,   // fragment-ordered, 48*512 halfs
    const _Float16* __restrict__ rs,    // fragment-ordered, 16*512 halfs
    const float* __restrict__ fb, const float* __restrict__ gb,
    const float* __restrict__ rb, const float* __restrict__ sb,
    const int dil, const float skip_scale)
{
    __shared__ _Float16 P0[64 * ST];    // 9.7KB
    __shared__ _Float16 P1[64 * ST];    // 9.7KB -> total 19.5KB

    const int tid  = threadIdx.x;
    const int lane = tid & 63;
    const int wv   = tid >> 6;          // 0..3
    const int ch32 = wv & 1;
    const int ch   = ch32 * 32;         // co-half
    const int tw   = (wv >> 1) * 32;    // t-half of the 64-t tile
    const int hl   = lane >> 5;
    const int ln31 = lane & 31;
    const int bb   = blockIdx.y;
    const int t0   = xcd_swizzle(blockIdx.x, Tn / 64) * 64;
    const size_t hbase = (size_t)bb * Tn * 64;

    v8h zero8;
    #pragma unroll
    for (int j = 0; j < 8; ++j) zero8[j] = (_Float16)0.f;

    const int s_tl = tid >> 3;              // base row (0..31), rows step 32
    const int s_c  = (tid & 7) * 8;

#define STAGE(DST, OFF) do {                                                  \
    _Pragma("unroll")                                                         \
    for (int it = 0; it < 2; ++it) {                                          \
        int tl = s_tl + it * 32;                                              \
        int tg = t0 + tl - (OFF);                                             \
        v8h v = zero8;                                                        \
        if (tg >= 0) v = *(const v8h*)&hin[hbase + (size_t)tg * 64 + s_c];    \
        *(v8h*)&(DST)[tl * ST + s_c] = v;                                     \
    } } while (0)

#define WOFF(TAP, KC, FG) (((((TAP) * 4 + (KC)) * 2 + (FG)) * 2 + ch32) * 512 + lane * 8)
#define RSOFF(KC, RSI)    ((((KC) * 2 + (RSI)) * 2 + ch32) * 512 + lane * 8)

#define MFMA_TAP(SRC, TAP) do {                                               \
    _Pragma("unroll")                                                         \
    for (int kc = 0; kc < 4; ++kc) {                                          \
        const int kof = kc * 16 + hl * 8;                                     \
        v8h aF = *(const v8h*)&wfg[WOFF(TAP, kc, 0)];                         \
        v8h aG = *(const v8h*)&wfg[WOFF(TAP, kc, 1)];                         \
        v8h b0 = *(const v8h*)&(SRC)[(tw + ln31) * ST + kof];                 \
        accF = __builtin_amdgcn_mfma_f32_32x32x16_f16(aF, b0, accF, 0, 0, 0); \
        accG = __builtin_amdgcn_mfma_f32_32x32x16_f16(aG, b0, accG, 0, 0, 0); \
    } } while (0)

    v16f accF, accG;
    #pragma unroll
    for (int q = 0; q < 4; ++q) {
        v4f fv = *(const v4f*)&fb[ch + 8 * q + 4 * hl];
        v4f gv = *(const v4f*)&gb[ch + 8 * q + 4 * hl];
        #pragma unroll
        for (int r = 0; r < 4; ++r) {
            accF[q * 4 + r] = fv[r];
            accG[q * 4 + r] = gv[r];
        }
    }

    STAGE(P0, 2 * dil);
    __syncthreads();                        // S1: P0 ready
    STAGE(P1, dil);                         // overlap tap1 loads with tap0 mfma
    MFMA_TAP(P0, 0);
    __syncthreads();                        // S2: P1 ready, P0 reads done
    STAGE(P0, 0);                           // overlap tap2 loads with tap1 mfma
    MFMA_TAP(P1, 1);
    __syncthreads();                        // S3: P0 ready, P1 reads done
    MFMA_TAP(P0, 2);                        // P0 now holds hin[t] (off=0) - kept

    #pragma unroll
    for (int q = 0; q < 4; ++q) {
        v4h av;
        #pragma unroll
        for (int r = 0; r < 4; ++r) {
            float f = accF[q * 4 + r];
            float g = accG[q * 4 + r];
            float A = __expf(2.f * f);
            float B = __expf(-g);
            float tA = A + 1.f;
            float den = fmaf(tA, B, tA);
            av[r] = (_Float16)((A - 1.f) * __builtin_amdgcn_rcpf(den));
        }
        *(v4h*)&P1[(tw + ln31) * ST + ch + 8 * q + 4 * hl] = av;
    }
    __syncthreads();                        // S4: act complete

    v16f accR, accS;
    #pragma unroll
    for (int q = 0; q < 4; ++q) {
        v4f rv = *(const v4f*)&rb[ch + 8 * q + 4 * hl];
        v4f sv = *(const v4f*)&sb[ch + 8 * q + 4 * hl];
        #pragma unroll
        for (int r = 0; r < 4; ++r) {
            accR[q * 4 + r] = rv[r];
            accS[q * 4 + r] = sv[r];
        }
    }

    #pragma unroll
    for (int kc = 0; kc < 4; ++kc) {
        const int kof = kc * 16 + hl * 8;
        v8h aR = *(const v8h*)&rs[RSOFF(kc, 0)];
        v8h aS = *(const v8h*)&rs[RSOFF(kc, 1)];
        v8h b0 = *(const v8h*)&P1[(tw + ln31) * ST + kof];
        accR = __builtin_amdgcn_mfma_f32_32x32x16_f16(aR, b0, accR, 0, 0, 0);
        accS = __builtin_amdgcn_mfma_f32_32x32x16_f16(aS, b0, accS, 0, 0, 0);
    }

    #pragma unroll
    for (int q = 0; q < 4; ++q) {
        _Float16* cell = &P0[(tw + ln31) * ST + ch + 8 * q + 4 * hl];
        v4h hv = *(const v4h*)cell;
        v4h hn;
        #pragma unroll
        for (int r = 0; r < 4; ++r)
            hn[r] = (_Float16)(((float)hv[r] + accR[q * 4 + r]) * 0.7071f);
        *(v4h*)cell = hn;
    }
    __syncthreads();                        // S5: P1 rs-reads done, P0 = hout tile

    #pragma unroll
    for (int q = 0; q < 4; ++q) {
        v4h sn;
        #pragma unroll
        for (int r = 0; r < 4; ++r)
            sn[r] = (_Float16)accS[q * 4 + r];
        *(v4h*)&P1[(tw + ln31) * ST + ch + 8 * q + 4 * hl] = sn;
    }
    #pragma unroll
    for (int it = 0; it < 2; ++it) {
        int tl = s_tl + it * 32;
        *(v8h*)&hout[hbase + (size_t)(t0 + tl) * 64 + s_c] = *(const v8h*)&P0[tl * ST + s_c];
    }
    __syncthreads();                        // S6: P1 skip tile complete

    #pragma unroll
    for (int it = 0; it < 2; ++it) {
        int tl = s_tl + it * 32;
        const size_t base = hbase + (size_t)(t0 + tl) * 64 + s_c;
        v8h sk = *(const v8h*)&skip[base];
        v8h pv = *(const v8h*)&P1[tl * ST + s_c];
        v8h sn;
        #pragma unroll
        for (int r = 0; r < 8; ++r)
            sn[r] = (_Float16)((float)sk[r] * skip_scale + (float)pv[r]);
        *(v8h*)&skip[base] = sn;
    }
#undef STAGE
#undef MFMA_TAP
#undef WOFF
#undef RSOFF
}

// ---------------------------------------------------------------------------
// k_out: out[b][t] = ow2 @ relu(ow1 @ relu(skip[b][t][:]) + ob1) + ob2
// ---------------------------------------------------------------------------
__global__ __launch_bounds__(256) void k_out(const _Float16* __restrict__ skip,
                                             const float* __restrict__ ow1,
                                             const float* __restrict__ ob1,
                                             const float* __restrict__ ow2,
                                             const float* __restrict__ ob2,
                                             float* __restrict__ out)
{
    const int blk = xcd_swizzle(blockIdx.x, Tn / 256);
    const int t  = blk * 256 + threadIdx.x;
    const int bb = blockIdx.y;
    const _Float16* sp = skip + ((size_t)bb * Tn + t) * 64;
    float y[64];
    #pragma unroll
    for (int i = 0; i < 8; ++i) {
        v8h v = *(const v8h*)&sp[i * 8];
        #pragma unroll
        for (int j = 0; j < 8; ++j) y[i * 8 + j] = fmaxf((float)v[j], 0.f);
    }
    float o = ob2[0];
    for (int co = 0; co < 64; ++co) {          // weights uniform -> s_loads
        float a0 = ob1[co], a1 = 0.f;
        #pragma unroll
        for (int ci = 0; ci < 64; ci += 2) {
            a0 = fmaf(ow1[co * 64 + ci],     y[ci],     a0);
            a1 = fmaf(ow1[co * 64 + ci + 1], y[ci + 1], a1);
        }
        o = fmaf(ow2[co], fmaxf(a0 + a1, 0.f), o);
    }
    out[(size_t)bb * Tn + t] = o;
}

// ---------------------------------------------------------------------------
extern "C" void kernel_launch(void* const* d_in, const int* in_sizes, int n_in,
                              void* d_out, int out_size, void* d_ws, size_t ws_size,
                              hipStream_t stream)
{
    const float* x    = (const float*)d_in[0];
    const float* w_in = (const float*)d_in[1];
    const float* b_in = (const float*)d_in[2];
    const float* fw   = (const float*)d_in[3];
    const float* fb   = (const float*)d_in[4];
    const float* gw   = (const float*)d_in[5];
    const float* gb   = (const float*)d_in[6];
    const float* rw   = (const float*)d_in[7];
    const float* rb   = (const float*)d_in[8];
    const float* sw   = (const float*)d_in[9];
    const float* sb   = (const float*)d_in[10];
    const float* ow1  = (const float*)d_in[11];
    const float* ob1  = (const float*)d_in[12];
    const float* ow2  = (const float*)d_in[13];
    const float* ob2  = (const float*)d_in[14];
    float* out = (float*)d_out;

    const size_t n = (size_t)Bn * Tn * 64;
    _Float16* hA    = (_Float16*)d_ws;
    _Float16* hB    = hA + n;
    _Float16* skip  = hB + n;
    _Float16* wfg16 = skip + n;
    _Float16* rs16  = wfg16 + (size_t)Ln * 24576;

    dim3 blk(256);
    k_prep<<<dim3((Ln * 24576 + Ln * 8192 + 255) / 256), blk, 0, stream>>>(
        fw, gw, rw, sw, wfg16, rs16);
    k_input<<<dim3(Tn / 256, Bn), blk, 0, stream>>>(x, w_in, b_in, hA);

    const _Float16* cur = hA;
    _Float16* nxt = hB;
    for (int l = 0; l < Ln; ++l) {
        const int d = 1 << l;                  // dilations 1..512
        if (d <= 32) {
            k_layer_u<<<dim3(Tn / 64, Bn), blk, 0, stream>>>(
                cur, nxt, skip,
                wfg16 + (size_t)l * 24576, rs16 + (size_t)l * 8192,
                fb + l * Cn, gb + l * Cn, rb + l * Cn, sb + l * Cn,
                d, (l == 0) ? 0.f : 1.f);      // scale=0 absorbs 0xAA ws poison
        } else {
            k_layer<<<dim3(Tn / 64, Bn), blk, 0, stream>>>(
                cur, nxt, skip,
                wfg16 + (size_t)l * 24576, rs16 + (size_t)l * 8192,
                fb + l * Cn, gb + l * Cn, rb + l * Cn, sb + l * Cn,
                d, 1.f);
        }
        const _Float16* tmp = nxt; nxt = (_Float16*)cur; cur = tmp;
    }

    k_out<<<dim3(Tn / 256, Bn), blk, 0, stream>>>(skip, ow1, ob1, ow2, ob2, out);
}